// Round 10
// baseline (127.999 us; speedup 1.0000x reference)
//
#include <hip/hip_runtime.h>
#include <hip/hip_bf16.h>
#include <stdint.h>

#define N_B 2
#define T_S 2048
#define D_M 1024
#define H_N 16
#define D_H 64

typedef __bf16 bf16_t;
typedef __bf16 bf16x8 __attribute__((ext_vector_type(8)));
typedef float f32x4 __attribute__((ext_vector_type(4)));
typedef float f32x16 __attribute__((ext_vector_type(16)));

__device__ __forceinline__ void async_ld16(const void* g, void* lds_uniform_base) {
  __builtin_amdgcn_global_load_lds(
      (const __attribute__((address_space(1))) uint32_t*)(uintptr_t)g,
      (__attribute__((address_space(3))) uint32_t*)(uintptr_t)lds_uniform_base,
      16, 0, 0);
}

// ---------------- fp32 -> bf16 convert (vectorized) ----------------
__global__ __launch_bounds__(256) void cvt_kernel(const float* __restrict__ in,
                                                  bf16_t* __restrict__ out, int n4) {
  int i = blockIdx.x * blockDim.x + threadIdx.x;
  if (i < n4) {
    float4 v = ((const float4*)in)[i];
    union { bf16_t b[4]; uint64_t u; } o;
    o.b[0] = (bf16_t)v.x; o.b[1] = (bf16_t)v.y;
    o.b[2] = (bf16_t)v.z; o.b[3] = (bf16_t)v.w;
    *(uint64_t*)(out + (size_t)i * 4) = o.u;
  }
}

// ---------------- fp32 -> bf16 convert + transpose (for W) ----------------
__global__ __launch_bounds__(256) void transpose_cvt_kernel(const float* __restrict__ in,
                                                            bf16_t* __restrict__ out,
                                                            int R, int C) {
  __shared__ float tile[32][33];
  int bx = blockIdx.x * 32;
  int by = blockIdx.y * 32;
  int tx = threadIdx.x, ty = threadIdx.y;  // (32,8)
#pragma unroll
  for (int i = 0; i < 32; i += 8)
    tile[ty + i][tx] = in[(size_t)(by + ty + i) * C + bx + tx];
  __syncthreads();
#pragma unroll
  for (int i = 0; i < 32; i += 8)
    out[(size_t)(bx + ty + i) * R + by + tx] = (bf16_t)tile[tx][ty + i];
}

// ---------------- proj GEMM: 128^2 m97 structure (MODE 1 only here) -------
template <int MODE>
__global__ __launch_bounds__(256) void gemm_bt_kernel(
    const bf16_t* __restrict__ A, const bf16_t* __restrict__ Bt,
    bf16_t* __restrict__ Qo, bf16_t* __restrict__ Ko, bf16_t* __restrict__ Vto,
    const float* __restrict__ bias, float* __restrict__ Co,
    int nbx, int cpx) {
  __shared__ bf16_t As[128 * 32];
  __shared__ bf16_t Bs[128 * 32];
  const int tid = threadIdx.x;
  const int lane = tid & 63;
  const int wid = tid >> 6;
  const int wr = wid >> 1, wc = wid & 1;
  const int g = lane >> 4, lr = lane & 15;
  const int d_ = blockIdx.x;
  const int orig = (d_ & 7) * cpx + (d_ >> 3);
  const int brow = (orig / nbx) * 128;
  const int bcol = (orig % nbx) * 128;

  f32x4 acc[4][4] = {};

  for (int k0 = 0; k0 < 1024; k0 += 32) {
#pragma unroll
    for (int q = 0; q < 2; ++q) {
      int idx = wid * 128 + q * 64 + lane;
      int row = idx >> 2, part = (idx & 3) * 8;
      async_ld16(A + (size_t)(brow + row) * 1024 + k0 + part,
                 &As[(wid * 128 + q * 64) * 8]);
      async_ld16(Bt + (size_t)(bcol + row) * 1024 + k0 + part,
                 &Bs[(wid * 128 + q * 64) * 8]);
    }
    __syncthreads();
    bf16x8 af[4], bfr[4];
#pragma unroll
    for (int i = 0; i < 4; ++i) {
      af[i]  = *(const bf16x8*)&As[(wr * 64 + i * 16 + lr) * 32 + g * 8];
      bfr[i] = *(const bf16x8*)&Bs[(wc * 64 + i * 16 + lr) * 32 + g * 8];
    }
#pragma unroll
    for (int i = 0; i < 4; ++i)
#pragma unroll
      for (int j = 0; j < 4; ++j)
        acc[i][j] = __builtin_amdgcn_mfma_f32_16x16x32_bf16(af[i], bfr[j], acc[i][j], 0, 0, 0);
    __syncthreads();
  }

#pragma unroll
  for (int i = 0; i < 4; ++i) {
    int row0 = brow + wr * 64 + i * 16 + g * 4;
#pragma unroll
    for (int j = 0; j < 4; ++j) {
      int col = bcol + wc * 64 + j * 16 + lr;
#pragma unroll
      for (int r = 0; r < 4; ++r) {
        int row = row0 + r;
        float v = acc[i][j][r];
        if (MODE == 0) {
          int n = row >> 11, t = row & (T_S - 1);
          int which = col >> 10, d = col & (D_M - 1);
          int h = d >> 6, dh = d & 63;
          if (which == 0)
            Qo[((size_t)(n * H_N + h) * T_S + t) * D_H + dh] = (bf16_t)v;
          else if (which == 1)
            Ko[((size_t)(n * H_N + h) * T_S + t) * D_H + dh] = (bf16_t)v;
          else
            Vto[((size_t)(n * H_N + h) * D_H + dh) * T_S + t] = (bf16_t)v;
        } else {
          Co[(size_t)row * D_M + col] = v + bias[col];
        }
      }
    }
  }
}

// ---------------- QKV GEMM: 256^2 8-phase (T2+T3+T4+T5) --------------------
// C[4096][3072] = A[4096][1024] @ Bt[3072][1024]^T, scatter into Q/K/Vt.
// 8 waves = 2M x 4N; per-wave output 128x64 (acc f32x4[8][4]).
// LDS 128KB: 2 dbuf x [A0|A1|B0|B1], half = [128 rows][64 k] bf16 (128B rows),
// XOR-swizzle byte^=(row&7)<<4 applied via pre-swizzled global src (write) and
// swizzled ds_read addr (read) -- same involution both sides.
// Pipeline: stage(t+1) -> s_waitcnt vmcnt(8) (counted: next tile in flight) ->
// barrier -> 4 phases of {ds_read 8/4 x b128; setprio1; 16 MFMA; setprio0;
// lgkmcnt(0); barrier}. lgkmcnt(0) before each barrier prevents in-flight
// ds_reads surviving past the barrier into the next tile's DMA overwrite.
__global__ __launch_bounds__(512, 2) void gemm_qkv8_kernel(
    const bf16_t* __restrict__ A, const bf16_t* __restrict__ Bt,
    bf16_t* __restrict__ Qo, bf16_t* __restrict__ Ko, bf16_t* __restrict__ Vto) {
  __shared__ bf16_t lds8[65536];  // 128 KB

  const int tid = threadIdx.x;   // 0..511
  const int lane = tid & 63;
  const int wv = tid >> 6;       // 0..7
  const int wm = wv >> 2;        // 0..1  (M half)
  const int wn = wv & 3;         // 0..3  (N quarter)
  const int lr = lane & 15, g = lane >> 4;
  const int swz = (lr & 7) << 4;

  // grid: 16 Mtiles x 12 Ntiles = 192 blocks; XCD-chunked swizzle cpx=24
  const int d_ = blockIdx.x;
  const int orig = (d_ & 7) * 24 + (d_ >> 3);
  const int brow = (orig / 12) * 256;
  const int bcol = (orig % 12) * 256;

  f32x4 acc[8][4] = {};

  auto stage = [&](int kt, int dbuf_) {
    char* ldsb = (char*)lds8 + dbuf_ * 65536;
#pragma unroll
    for (int q = 0; q < 8; ++q) {
      int ch = q * 512 + tid;          // 0..4095 chunk of 16B
      int sec = ch >> 10;              // 0,1 = A halves; 2,3 = B halves
      int cs = ch & 1023;
      int r = cs >> 3, cb = (cs & 7) * 16;
      int srcb = cb ^ ((r & 7) << 4);  // pre-swizzled k-window byte
      const char* gsrc;
      if (sec < 2)
        gsrc = (const char*)A + (size_t)(brow + sec * 128 + r) * 2048 + kt * 128 + srcb;
      else
        gsrc = (const char*)Bt + (size_t)(bcol + (sec - 2) * 128 + r) * 2048 + kt * 128 + srcb;
      async_ld16(gsrc, ldsb + (q * 512 + wv * 64) * 16);  // wave-uniform dest
    }
  };

  stage(0, 0);
  for (int t = 0; t < 16; ++t) {
    const int db = t & 1;
    if (t + 1 < 16) {
      stage(t + 1, db ^ 1);
      asm volatile("s_waitcnt vmcnt(8)" ::: "memory");  // tile t landed; t+1 in flight
    } else {
      asm volatile("s_waitcnt vmcnt(0)" ::: "memory");
    }
    __builtin_amdgcn_s_barrier();
    __builtin_amdgcn_sched_barrier(0);

    const char* Abase = (const char*)lds8 + db * 65536 + wm * 16384;
    const char* Bbase = (const char*)lds8 + db * 65536 + 32768 + (wn >> 1) * 16384 + (wn & 1) * 8192;

#pragma unroll
    for (int b = 0; b < 2; ++b) {
      bf16x8 bfr[4];
#pragma unroll
      for (int nf = 0; nf < 4; ++nf)
        bfr[nf] = *(const bf16x8*)(Bbase + ((nf * 2048 + lr * 128 + b * 64 + g * 16) ^ swz));
#pragma unroll
      for (int half = 0; half < 2; ++half) {
        bf16x8 af[4];
#pragma unroll
        for (int i = 0; i < 4; ++i)
          af[i] = *(const bf16x8*)(Abase + (((half * 4 + i) * 2048 + lr * 128 + b * 64 + g * 16) ^ swz));
        __builtin_amdgcn_s_setprio(1);
#pragma unroll
        for (int i = 0; i < 4; ++i)
#pragma unroll
          for (int nf = 0; nf < 4; ++nf)
            acc[half * 4 + i][nf] =
                __builtin_amdgcn_mfma_f32_16x16x32_bf16(af[i], bfr[nf], acc[half * 4 + i][nf], 0, 0, 0);
        __builtin_amdgcn_s_setprio(0);
        asm volatile("s_waitcnt lgkmcnt(0)" ::: "memory");  // reads retired before barrier
        __builtin_amdgcn_s_barrier();
      }
    }
  }

  // epilogue: scatter into Q/K/Vt head layouts
#pragma unroll
  for (int mf = 0; mf < 8; ++mf) {
    int row0 = brow + wm * 128 + mf * 16 + g * 4;
#pragma unroll
    for (int nf = 0; nf < 4; ++nf) {
      int col = bcol + wn * 64 + nf * 16 + lr;
      int which = col >> 10, dcol = col & (D_M - 1);
      int hh = dcol >> 6, dh = dcol & 63;
#pragma unroll
      for (int r = 0; r < 4; ++r) {
        int row = row0 + r;
        int nn = row >> 11, tt = row & (T_S - 1);
        float v = acc[mf][nf][r];
        if (which == 0)
          Qo[((size_t)(nn * H_N + hh) * T_S + tt) * D_H + dh] = (bf16_t)v;
        else if (which == 1)
          Ko[((size_t)(nn * H_N + hh) * T_S + tt) * D_H + dh] = (bf16_t)v;
        else
          Vto[((size_t)(nn * H_N + hh) * D_H + dh) * T_S + tt] = (bf16_t)v;
      }
    }
  }
}

// ---------------- causal flash attention (swapped-QK, 32x32 MFMA) ----------
// (r9 structure, unchanged)
__global__ __launch_bounds__(256, 4) void attn_kernel(const bf16_t* __restrict__ Q,
                                                      const bf16_t* __restrict__ K,
                                                      const bf16_t* __restrict__ Vt,
                                                      bf16_t* __restrict__ O) {
  __shared__ bf16_t Ks[2][4096];
  __shared__ bf16_t Vs[2][4096];
  __shared__ float Linv[64];

  const int tid = threadIdx.x;
  const int lane = tid & 63;
  const int w = tid >> 6;
  const int qsub = w >> 1, khalf = w & 1;
  const int l31 = lane & 31;
  const int hi = lane >> 5;

  const int d_ = blockIdx.x;       // 0..1023
  const int x = d_ & 7;
  const int s = d_ >> 3;
  const int hs = s & 3, j_ = s >> 2;
  const int t_ = j_ >> 3, m_ = j_ & 7;
  const int qc = (t_ == 0) ? (31 - m_) : (t_ == 1) ? (16 + m_)
               : (t_ == 2) ? (15 - m_) : m_;
  const int nh = x * 4 + hs;
  const bf16_t* Qg = Q + (size_t)nh * T_S * D_H;
  const char* Kb = (const char*)(K + (size_t)nh * T_S * D_H);
  const char* Vb = (const char*)(Vt + (size_t)nh * D_H * T_S);
  const int n = nh >> 4, h = nh & 15;

  const int c0 = (w * 2 + 0) * 64 + lane;
  const int c1 = (w * 2 + 1) * 64 + lane;
  const int r0_ = c0 >> 3, cb0 = (c0 & 7) * 16, sw0 = (r0_ & 7) << 4;
  const int r1_ = c1 >> 3, cb1 = (c1 & 7) * 16, sw1 = (r1_ & 7) << 4;
  const int koff0 = r0_ * 128 + (cb0 ^ sw0), koff1 = r1_ * 128 + (cb1 ^ sw1);
  const int voff0 = r0_ * 4096 + (cb0 ^ sw0), voff1 = r1_ * 4096 + (cb1 ^ sw1);
  const int lds0 = (w * 2 + 0) * 1024, lds1 = (w * 2 + 1) * 1024;

  const int q0w = qc * 64 + qsub * 32;
  const int nt = qc + 1;

  bf16x8 qf[4];
#pragma unroll
  for (int ksd = 0; ksd < 4; ++ksd) {
    bf16x8 t = *(const bf16x8*)(Qg + (size_t)(q0w + l31) * D_H + ksd * 16 + hi * 8);
#pragma unroll
    for (int e = 0; e < 8; ++e) t[e] = (bf16_t)((float)t[e] * 0.125f);
    qf[ksd] = t;
  }

  const int kabs_ = khalf * 32 + l31;
  int kfo[4];
#pragma unroll
  for (int ksd = 0; ksd < 4; ++ksd)
    kfo[ksd] = (kabs_ * 128 + ksd * 32 + hi * 16) ^ ((kabs_ & 7) << 4);
  int vfo[2][2];
#pragma unroll
  for (int db = 0; db < 2; ++db)
#pragma unroll
    for (int kk = 0; kk < 2; ++kk) {
      int dd = db * 32 + l31;
      vfo[db][kk] = (dd * 128 + khalf * 64 + kk * 32 + hi * 16) ^ ((dd & 7) << 4);
    }

  f32x16 oacc[2] = {};
  float lsum = 0.f;

  auto issue = [&](int t, int b) {
    const char* kt_ = Kb + (size_t)t * 8192;
    const char* vt_ = Vb + (size_t)t * 128;
    async_ld16(kt_ + koff0, (char*)Ks[b] + lds0);
    async_ld16(kt_ + koff1, (char*)Ks[b] + lds1);
    async_ld16(vt_ + voff0, (char*)Vs[b] + lds0);
    async_ld16(vt_ + voff1, (char*)Vs[b] + lds1);
  };

  auto compute = [&](int kt, int b, bool domask) {
    f32x16 S = {};
    __builtin_amdgcn_s_setprio(1);
#pragma unroll
    for (int ksd = 0; ksd < 4; ++ksd) {
      bf16x8 kf = *(const bf16x8*)((char*)Ks[b] + kfo[ksd]);
      S = __builtin_amdgcn_mfma_f32_32x32x16_bf16(kf, qf[ksd], S, 0, 0, 0);
    }
    __builtin_amdgcn_s_setprio(0);

    if (domask) {
#pragma unroll
      for (int r = 0; r < 16; ++r) {
        int ktile = khalf * 32 + (r & 3) + 8 * (r >> 2) + 4 * hi;
        if (kt * 64 + ktile > q0w + l31) S[r] = -1.0e30f;
      }
    }

    float p[16];
#pragma unroll
    for (int r = 0; r < 16; ++r) {
      p[r] = __builtin_amdgcn_exp2f(fminf(S[r] * 1.442695041f, 50.f));
      lsum += p[r];
    }

    uint32_t dw[8];
#pragma unroll
    for (int i = 0; i < 8; ++i) {
      union { bf16_t b2[2]; uint32_t u; } pk;
      pk.b2[0] = (bf16_t)p[2 * i];
      pk.b2[1] = (bf16_t)p[2 * i + 1];
      dw[i] = pk.u;
    }

    bf16x8 pa[2];
#pragma unroll
    for (int kk = 0; kk < 2; ++kk) {
      uint32_t u0 = dw[kk * 4 + 0], u1 = dw[kk * 4 + 1];
      uint32_t u2 = dw[kk * 4 + 2], u3 = dw[kk * 4 + 3];
      uint32_t sa = __shfl_xor(hi ? u0 : u2, 32, 64);
      uint32_t sb = __shfl_xor(hi ? u1 : u3, 32, 64);
      union { uint32_t u[4]; bf16x8 v; } f;
      f.u[0] = hi ? sa : u0;
      f.u[1] = hi ? sb : u1;
      f.u[2] = hi ? u2 : sa;
      f.u[3] = hi ? u3 : sb;
      pa[kk] = f.v;
    }

    __builtin_amdgcn_s_setprio(1);
#pragma unroll
    for (int db = 0; db < 2; ++db)
#pragma unroll
      for (int kk = 0; kk < 2; ++kk) {
        bf16x8 vf = *(const bf16x8*)((char*)Vs[b] + vfo[db][kk]);
        oacc[db] = __builtin_amdgcn_mfma_f32_32x32x16_bf16(pa[kk], vf, oacc[db], 0, 0, 0);
      }
    __builtin_amdgcn_s_setprio(0);
  };

  issue(0, 0);
  int buf = 0;
  for (int kt = 0; kt < nt; ++kt) {
    asm volatile("s_waitcnt vmcnt(0)" ::: "memory");
    __builtin_amdgcn_s_barrier();
    __builtin_amdgcn_sched_barrier(0);
    if (kt + 1 < nt) issue(kt + 1, buf ^ 1);
    compute(kt, buf, kt == nt - 1);
    buf ^= 1;
  }

  lsum += __shfl_xor(lsum, 32, 64);

  __syncthreads();
  float* mO = (float*)Ks;
  float* mL = (float*)Vs;
  if (khalf == 1) {
    float* ob = mO + qsub * 2048;
#pragma unroll
    for (int db = 0; db < 2; ++db)
#pragma unroll
      for (int r = 0; r < 16; ++r)
        ob[(db * 16 + r) * 64 + lane] = oacc[db][r];
    mL[qsub * 32 + l31] = lsum;
  }
  __syncthreads();
  if (khalf == 0) {
    float* ob = mO + qsub * 2048;
    float ltot = lsum + mL[qsub * 32 + l31];
    Linv[qsub * 32 + l31] = 1.f / ltot;
#pragma unroll
    for (int db = 0; db < 2; ++db)
#pragma unroll
      for (int r = 0; r < 16; ++r)
        oacc[db][r] += ob[(db * 16 + r) * 64 + lane];
#pragma unroll
    for (int r = 0; r < 16; ++r) {
      int ro = (r & 3) + 8 * (r >> 2) + 4 * hi;
      int qrow = q0w + ro;
      float inv = Linv[qsub * 32 + ro];
#pragma unroll
      for (int db = 0; db < 2; ++db)
        O[(size_t)(n * T_S + qrow) * D_M + h * D_H + db * 32 + l31] =
            (bf16_t)(oacc[db][r] * inv);
    }
  }
}

extern "C" void kernel_launch(void* const* d_in, const int* in_sizes, int n_in,
                              void* d_out, int out_size, void* d_ws, size_t ws_size,
                              hipStream_t stream) {
  const float* x  = (const float*)d_in[0];
  const float* W  = (const float*)d_in[1];
  const float* pw = (const float*)d_in[2];
  const float* pb = (const float*)d_in[3];
  float* out = (float*)d_out;

  char* ws = (char*)d_ws;
  bf16_t* x_bf = (bf16_t*)(ws);                      //  8 MB: [4096][1024]
  bf16_t* Wt   = (bf16_t*)(ws + (8ull  << 20));      //  6 MB: [3072][1024]
  bf16_t* pwb  = (bf16_t*)(ws + (14ull << 20));      //  2 MB: [1024][1024]
  bf16_t* Qh   = (bf16_t*)(ws + (16ull << 20));      //  8 MB: [2,16,2048,64]
  bf16_t* Kh   = (bf16_t*)(ws + (24ull << 20));      //  8 MB
  bf16_t* Vth  = (bf16_t*)(ws + (32ull << 20));      //  8 MB: [2,16,64,2048]
  bf16_t* Oa   = (bf16_t*)(ws + (40ull << 20));      //  8 MB: [4096][1024]

  cvt_kernel<<<4096, 256, 0, stream>>>(x, x_bf, (4096 * 1024) / 4);
  transpose_cvt_kernel<<<dim3(96, 32), dim3(32, 8), 0, stream>>>(W, Wt, 1024, 3072);
  cvt_kernel<<<1024, 256, 0, stream>>>(pw, pwb, (1024 * 1024) / 4);

  // QKV GEMM: 256^2 8-phase, 16x12 = 192 blocks, 512 threads
  gemm_qkv8_kernel<<<192, 512, 0, stream>>>(x_bf, Wt, Qh, Kh, Vth);

  attn_kernel<<<1024, 256, 0, stream>>>(Qh, Kh, Vth, Oa);

  // proj GEMM: M=4096, N=1024 -> 256 blocks, cpx=32 (128^2 structure)
  gemm_bt_kernel<1><<<256, 256, 0, stream>>>(Oa, pwb, nullptr, nullptr, nullptr, pb, out, 8, 32);
}

// Round 11
// 112.525 us; speedup vs baseline: 1.1375x; 1.1375x over previous
//
#include <hip/hip_runtime.h>
#include <hip/hip_bf16.h>
#include <stdint.h>

#define N_B 2
#define T_S 2048
#define D_M 1024
#define H_N 16
#define D_H 64

typedef __bf16 bf16_t;
typedef __bf16 bf16x8 __attribute__((ext_vector_type(8)));
typedef float f32x4 __attribute__((ext_vector_type(4)));
typedef float f32x16 __attribute__((ext_vector_type(16)));

__device__ __forceinline__ void async_ld16(const void* g, void* lds_uniform_base) {
  __builtin_amdgcn_global_load_lds(
      (const __attribute__((address_space(1))) uint32_t*)(uintptr_t)g,
      (__attribute__((address_space(3))) uint32_t*)(uintptr_t)lds_uniform_base,
      16, 0, 0);
}

// ---------------- fp32 -> bf16 convert (x and proj_w fused) ----------------
__global__ __launch_bounds__(256) void cvt2_kernel(const float* __restrict__ in1,
                                                   bf16_t* __restrict__ out1, int n1,
                                                   const float* __restrict__ in2,
                                                   bf16_t* __restrict__ out2) {
  int i = blockIdx.x * blockDim.x + threadIdx.x;
  const float* in = in1;
  bf16_t* out = out1;
  if (i >= n1) { i -= n1; in = in2; out = out2; }
  float4 v = ((const float4*)in)[i];
  union { bf16_t b[4]; uint64_t u; } o;
  o.b[0] = (bf16_t)v.x; o.b[1] = (bf16_t)v.y;
  o.b[2] = (bf16_t)v.z; o.b[3] = (bf16_t)v.w;
  *(uint64_t*)(out + (size_t)i * 4) = o.u;
}

// ---------------- fp32 -> bf16 convert + transpose (for W) ----------------
__global__ __launch_bounds__(256) void transpose_cvt_kernel(const float* __restrict__ in,
                                                            bf16_t* __restrict__ out,
                                                            int R, int C) {
  __shared__ float tile[32][33];
  int bx = blockIdx.x * 32;
  int by = blockIdx.y * 32;
  int tx = threadIdx.x, ty = threadIdx.y;  // (32,8)
#pragma unroll
  for (int i = 0; i < 32; i += 8)
    tile[ty + i][tx] = in[(size_t)(by + ty + i) * C + bx + tx];
  __syncthreads();
#pragma unroll
  for (int i = 0; i < 32; i += 8)
    out[(size_t)(bx + ty + i) * R + by + tx] = (bf16_t)tile[tx][ty + i];
}

// ---------------- bf16 GEMM, C = A @ Bt^T : 128^2 tile, BK=64 -------------
// A: [M][1024], Bt: [N][1024] bf16 row-major.
// LDS 64KB: 2 dbuf x (A[128][64] + B[128][64]) with 128B rows, XOR-swizzle
// byte ^= (row&7)<<4 (proven 0-conflict in attn/r10): pre-swizzled global
// source (write side) + swizzled ds_read addr (read side).
// Pipeline: stage(t+1) -> counted vmcnt(8) (tile t landed, t+1 in flight) ->
// barrier -> 32 MFMA/wave (compiler-scheduled lgkmcnt) -> barrier.
// MODE 0: scatter into Q/K/Vt head layouts.  MODE 1: +bias, fp32 out.
template <int MODE>
__global__ __launch_bounds__(256) void gemm_bt_kernel(
    const bf16_t* __restrict__ A, const bf16_t* __restrict__ Bt,
    bf16_t* __restrict__ Qo, bf16_t* __restrict__ Ko, bf16_t* __restrict__ Vto,
    const float* __restrict__ bias, float* __restrict__ Co,
    int nbx, int cpx) {
  __shared__ bf16_t lds[32768];  // 64 KB: [buf][A|B][128 rows][128B]
  const int tid = threadIdx.x;
  const int lane = tid & 63;
  const int wid = tid >> 6;
  const int wr = wid >> 1, wc = wid & 1;
  const int g = lane >> 4, lr = lane & 15;
  const int d_ = blockIdx.x;
  const int orig = (d_ & 7) * cpx + (d_ >> 3);
  const int brow = (orig / nbx) * 128;
  const int bcol = (orig % nbx) * 128;

  f32x4 acc[4][4] = {};

  // staging geometry: 2048 x 16B chunks per K-tile (A:1024, B:1024), 8/thread
  int srow[8], scb[8], sdst[8];
#pragma unroll
  for (int q = 0; q < 8; ++q) {
    int c = q * 256 + tid;
    int sec = c >> 10;              // 0 = A, 1 = B
    int cs = c & 1023;
    int row = cs >> 3, col = cs & 7;
    srow[q] = row;
    scb[q] = (col * 16) ^ ((row & 7) << 4);  // pre-swizzled source byte
    sdst[q] = sec * 16384 + cs * 16;         // linear LDS byte (per-buf)
  }

  auto stage = [&](int t, int b) {
    char* base = (char*)lds + b * 32768;
#pragma unroll
    for (int q = 0; q < 8; ++q) {
      const char* gsrc = (q < 4)
          ? (const char*)A + (size_t)(brow + srow[q]) * 2048 + t * 128 + scb[q]
          : (const char*)Bt + (size_t)(bcol + srow[q]) * 2048 + t * 128 + scb[q];
      async_ld16(gsrc, base + sdst[q]);
    }
  };

  stage(0, 0);
  for (int t = 0; t < 16; ++t) {
    if (t + 1 < 16) {
      stage(t + 1, (t + 1) & 1);
      asm volatile("s_waitcnt vmcnt(8)" ::: "memory");
    } else {
      asm volatile("s_waitcnt vmcnt(0)" ::: "memory");
    }
    __builtin_amdgcn_s_barrier();
    __builtin_amdgcn_sched_barrier(0);

    const char* base = (const char*)lds + (t & 1) * 32768;
#pragma unroll
    for (int b = 0; b < 2; ++b) {  // k-steps of 32
      bf16x8 af[4], bfr[4];
#pragma unroll
      for (int i = 0; i < 4; ++i) {
        int ra = wr * 64 + i * 16 + lr;
        int rb = wc * 64 + i * 16 + lr;
        af[i]  = *(const bf16x8*)(base + ra * 128 + ((b * 64 + g * 16) ^ ((ra & 7) << 4)));
        bfr[i] = *(const bf16x8*)(base + 16384 + rb * 128 + ((b * 64 + g * 16) ^ ((rb & 7) << 4)));
      }
      __builtin_amdgcn_s_setprio(1);
#pragma unroll
      for (int i = 0; i < 4; ++i)
#pragma unroll
        for (int j = 0; j < 4; ++j)
          acc[i][j] = __builtin_amdgcn_mfma_f32_16x16x32_bf16(af[i], bfr[j], acc[i][j], 0, 0, 0);
      __builtin_amdgcn_s_setprio(0);
    }
    asm volatile("s_waitcnt lgkmcnt(0)" ::: "memory");
    __builtin_amdgcn_s_barrier();  // reads retired before next stage overwrites
  }

#pragma unroll
  for (int i = 0; i < 4; ++i) {
    int row0 = brow + wr * 64 + i * 16 + g * 4;
#pragma unroll
    for (int j = 0; j < 4; ++j) {
      int col = bcol + wc * 64 + j * 16 + lr;
#pragma unroll
      for (int r = 0; r < 4; ++r) {
        int row = row0 + r;
        float v = acc[i][j][r];
        if (MODE == 0) {
          int n = row >> 11, t = row & (T_S - 1);
          int which = col >> 10, d = col & (D_M - 1);
          int h = d >> 6, dh = d & 63;
          if (which == 0)
            Qo[((size_t)(n * H_N + h) * T_S + t) * D_H + dh] = (bf16_t)v;
          else if (which == 1)
            Ko[((size_t)(n * H_N + h) * T_S + t) * D_H + dh] = (bf16_t)v;
          else
            Vto[((size_t)(n * H_N + h) * D_H + dh) * T_S + t] = (bf16_t)v;
        } else {
          Co[(size_t)row * D_M + col] = v + bias[col];
        }
      }
    }
  }
}

// ---------------- causal flash attention (swapped-QK, 32x32 MFMA) ----------
// (r9 structure, unchanged)
__global__ __launch_bounds__(256, 4) void attn_kernel(const bf16_t* __restrict__ Q,
                                                      const bf16_t* __restrict__ K,
                                                      const bf16_t* __restrict__ Vt,
                                                      bf16_t* __restrict__ O) {
  __shared__ bf16_t Ks[2][4096];
  __shared__ bf16_t Vs[2][4096];
  __shared__ float Linv[64];

  const int tid = threadIdx.x;
  const int lane = tid & 63;
  const int w = tid >> 6;
  const int qsub = w >> 1, khalf = w & 1;
  const int l31 = lane & 31;
  const int hi = lane >> 5;

  const int d_ = blockIdx.x;       // 0..1023
  const int x = d_ & 7;
  const int s = d_ >> 3;
  const int hs = s & 3, j_ = s >> 2;
  const int t_ = j_ >> 3, m_ = j_ & 7;
  const int qc = (t_ == 0) ? (31 - m_) : (t_ == 1) ? (16 + m_)
               : (t_ == 2) ? (15 - m_) : m_;
  const int nh = x * 4 + hs;
  const bf16_t* Qg = Q + (size_t)nh * T_S * D_H;
  const char* Kb = (const char*)(K + (size_t)nh * T_S * D_H);
  const char* Vb = (const char*)(Vt + (size_t)nh * D_H * T_S);
  const int n = nh >> 4, h = nh & 15;

  const int c0 = (w * 2 + 0) * 64 + lane;
  const int c1 = (w * 2 + 1) * 64 + lane;
  const int r0_ = c0 >> 3, cb0 = (c0 & 7) * 16, sw0 = (r0_ & 7) << 4;
  const int r1_ = c1 >> 3, cb1 = (c1 & 7) * 16, sw1 = (r1_ & 7) << 4;
  const int koff0 = r0_ * 128 + (cb0 ^ sw0), koff1 = r1_ * 128 + (cb1 ^ sw1);
  const int voff0 = r0_ * 4096 + (cb0 ^ sw0), voff1 = r1_ * 4096 + (cb1 ^ sw1);
  const int lds0 = (w * 2 + 0) * 1024, lds1 = (w * 2 + 1) * 1024;

  const int q0w = qc * 64 + qsub * 32;
  const int nt = qc + 1;

  bf16x8 qf[4];
#pragma unroll
  for (int ksd = 0; ksd < 4; ++ksd) {
    bf16x8 t = *(const bf16x8*)(Qg + (size_t)(q0w + l31) * D_H + ksd * 16 + hi * 8);
#pragma unroll
    for (int e = 0; e < 8; ++e) t[e] = (bf16_t)((float)t[e] * 0.125f);
    qf[ksd] = t;
  }

  const int kabs_ = khalf * 32 + l31;
  int kfo[4];
#pragma unroll
  for (int ksd = 0; ksd < 4; ++ksd)
    kfo[ksd] = (kabs_ * 128 + ksd * 32 + hi * 16) ^ ((kabs_ & 7) << 4);
  int vfo[2][2];
#pragma unroll
  for (int db = 0; db < 2; ++db)
#pragma unroll
    for (int kk = 0; kk < 2; ++kk) {
      int dd = db * 32 + l31;
      vfo[db][kk] = (dd * 128 + khalf * 64 + kk * 32 + hi * 16) ^ ((dd & 7) << 4);
    }

  f32x16 oacc[2] = {};
  float lsum = 0.f;

  auto issue = [&](int t, int b) {
    const char* kt_ = Kb + (size_t)t * 8192;
    const char* vt_ = Vb + (size_t)t * 128;
    async_ld16(kt_ + koff0, (char*)Ks[b] + lds0);
    async_ld16(kt_ + koff1, (char*)Ks[b] + lds1);
    async_ld16(vt_ + voff0, (char*)Vs[b] + lds0);
    async_ld16(vt_ + voff1, (char*)Vs[b] + lds1);
  };

  auto compute = [&](int kt, int b, bool domask) {
    f32x16 S = {};
    __builtin_amdgcn_s_setprio(1);
#pragma unroll
    for (int ksd = 0; ksd < 4; ++ksd) {
      bf16x8 kf = *(const bf16x8*)((char*)Ks[b] + kfo[ksd]);
      S = __builtin_amdgcn_mfma_f32_32x32x16_bf16(kf, qf[ksd], S, 0, 0, 0);
    }
    __builtin_amdgcn_s_setprio(0);

    if (domask) {
#pragma unroll
      for (int r = 0; r < 16; ++r) {
        int ktile = khalf * 32 + (r & 3) + 8 * (r >> 2) + 4 * hi;
        if (kt * 64 + ktile > q0w + l31) S[r] = -1.0e30f;
      }
    }

    float p[16];
#pragma unroll
    for (int r = 0; r < 16; ++r) {
      p[r] = __builtin_amdgcn_exp2f(fminf(S[r] * 1.442695041f, 50.f));
      lsum += p[r];
    }

    uint32_t dw[8];
#pragma unroll
    for (int i = 0; i < 8; ++i) {
      union { bf16_t b2[2]; uint32_t u; } pk;
      pk.b2[0] = (bf16_t)p[2 * i];
      pk.b2[1] = (bf16_t)p[2 * i + 1];
      dw[i] = pk.u;
    }

    bf16x8 pa[2];
#pragma unroll
    for (int kk = 0; kk < 2; ++kk) {
      uint32_t u0 = dw[kk * 4 + 0], u1 = dw[kk * 4 + 1];
      uint32_t u2 = dw[kk * 4 + 2], u3 = dw[kk * 4 + 3];
      uint32_t sa = __shfl_xor(hi ? u0 : u2, 32, 64);
      uint32_t sb = __shfl_xor(hi ? u1 : u3, 32, 64);
      union { uint32_t u[4]; bf16x8 v; } f;
      f.u[0] = hi ? sa : u0;
      f.u[1] = hi ? sb : u1;
      f.u[2] = hi ? u2 : sa;
      f.u[3] = hi ? u3 : sb;
      pa[kk] = f.v;
    }

    __builtin_amdgcn_s_setprio(1);
#pragma unroll
    for (int db = 0; db < 2; ++db)
#pragma unroll
      for (int kk = 0; kk < 2; ++kk) {
        bf16x8 vf = *(const bf16x8*)((char*)Vs[b] + vfo[db][kk]);
        oacc[db] = __builtin_amdgcn_mfma_f32_32x32x16_bf16(pa[kk], vf, oacc[db], 0, 0, 0);
      }
    __builtin_amdgcn_s_setprio(0);
  };

  issue(0, 0);
  int buf = 0;
  for (int kt = 0; kt < nt; ++kt) {
    asm volatile("s_waitcnt vmcnt(0)" ::: "memory");
    __builtin_amdgcn_s_barrier();
    __builtin_amdgcn_sched_barrier(0);
    if (kt + 1 < nt) issue(kt + 1, buf ^ 1);
    compute(kt, buf, kt == nt - 1);
    buf ^= 1;
  }

  lsum += __shfl_xor(lsum, 32, 64);

  __syncthreads();
  float* mO = (float*)Ks;
  float* mL = (float*)Vs;
  if (khalf == 1) {
    float* ob = mO + qsub * 2048;
#pragma unroll
    for (int db = 0; db < 2; ++db)
#pragma unroll
      for (int r = 0; r < 16; ++r)
        ob[(db * 16 + r) * 64 + lane] = oacc[db][r];
    mL[qsub * 32 + l31] = lsum;
  }
  __syncthreads();
  if (khalf == 0) {
    float* ob = mO + qsub * 2048;
    float ltot = lsum + mL[qsub * 32 + l31];
    Linv[qsub * 32 + l31] = 1.f / ltot;
#pragma unroll
    for (int db = 0; db < 2; ++db)
#pragma unroll
      for (int r = 0; r < 16; ++r)
        oacc[db][r] += ob[(db * 16 + r) * 64 + lane];
#pragma unroll
    for (int r = 0; r < 16; ++r) {
      int ro = (r & 3) + 8 * (r >> 2) + 4 * hi;
      int qrow = q0w + ro;
      float inv = Linv[qsub * 32 + ro];
#pragma unroll
      for (int db = 0; db < 2; ++db)
        O[(size_t)(n * T_S + qrow) * D_M + h * D_H + db * 32 + l31] =
            (bf16_t)(oacc[db][r] * inv);
    }
  }
}

extern "C" void kernel_launch(void* const* d_in, const int* in_sizes, int n_in,
                              void* d_out, int out_size, void* d_ws, size_t ws_size,
                              hipStream_t stream) {
  const float* x  = (const float*)d_in[0];
  const float* W  = (const float*)d_in[1];
  const float* pw = (const float*)d_in[2];
  const float* pb = (const float*)d_in[3];
  float* out = (float*)d_out;

  char* ws = (char*)d_ws;
  bf16_t* x_bf = (bf16_t*)(ws);                      //  8 MB: [4096][1024]
  bf16_t* Wt   = (bf16_t*)(ws + (8ull  << 20));      //  6 MB: [3072][1024]
  bf16_t* pwb  = (bf16_t*)(ws + (14ull << 20));      //  2 MB: [1024][1024]
  bf16_t* Qh   = (bf16_t*)(ws + (16ull << 20));      //  8 MB: [2,16,2048,64]
  bf16_t* Kh   = (bf16_t*)(ws + (24ull << 20));      //  8 MB
  bf16_t* Vth  = (bf16_t*)(ws + (32ull << 20));      //  8 MB: [2,16,64,2048]
  bf16_t* Oa   = (bf16_t*)(ws + (40ull << 20));      //  8 MB: [4096][1024]

  // x (4M elems) + proj_w (1M elems) converts fused: 5120 blocks
  cvt2_kernel<<<5120, 256, 0, stream>>>(x, x_bf, (4096 * 1024) / 4, pw, pwb);
  transpose_cvt_kernel<<<dim3(96, 32), dim3(32, 8), 0, stream>>>(W, Wt, 1024, 3072);

  // QKV GEMM: M=4096 (32), N=3072 (24) -> 768 blocks, cpx=96
  gemm_bt_kernel<0><<<768, 256, 0, stream>>>(x_bf, Wt, Qh, Kh, Vth, nullptr, nullptr, 24, 96);

  attn_kernel<<<1024, 256, 0, stream>>>(Qh, Kh, Vth, Oa);

  // proj GEMM: M=4096 (32), N=1024 (8) -> 256 blocks, cpx=32
  gemm_bt_kernel<1><<<256, 256, 0, stream>>>(Oa, pwb, nullptr, nullptr, nullptr, pb, out, 8, 32);
}

// Round 12
// 102.255 us; speedup vs baseline: 1.2518x; 1.1004x over previous
//
#include <hip/hip_runtime.h>
#include <hip/hip_bf16.h>
#include <stdint.h>

#define N_B 2
#define T_S 2048
#define D_M 1024
#define H_N 16
#define D_H 64

typedef __bf16 bf16_t;
typedef __bf16 bf16x8 __attribute__((ext_vector_type(8)));
typedef float f32x4 __attribute__((ext_vector_type(4)));
typedef float f32x16 __attribute__((ext_vector_type(16)));

__device__ __forceinline__ void async_ld16(const void* g, void* lds_uniform_base) {
  __builtin_amdgcn_global_load_lds(
      (const __attribute__((address_space(1))) uint32_t*)(uintptr_t)g,
      (__attribute__((address_space(3))) uint32_t*)(uintptr_t)lds_uniform_base,
      16, 0, 0);
}

// ---------------- prep: fp32->bf16 cvt (x, proj_w) + W transpose-cvt -------
// blocks [0,5120): cvt x (4M elems) then proj_w (1M elems), float4/thread.
// blocks [5120,8192): 32x32 transpose tiles of W [1024][3072] -> Wt [3072][1024].
__global__ __launch_bounds__(256) void prep_kernel(
    const float* __restrict__ x, bf16_t* __restrict__ x_bf,
    const float* __restrict__ pw, bf16_t* __restrict__ pwb,
    const float* __restrict__ W, bf16_t* __restrict__ Wt) {
  __shared__ float tile[32][33];
  const int bid = blockIdx.x;
  if (bid < 5120) {
    int i = bid * 256 + threadIdx.x;
    const float* in = x;
    bf16_t* out = x_bf;
    const int n1 = (4096 * 1024) / 4;
    if (i >= n1) { i -= n1; in = pw; out = pwb; }
    float4 v = ((const float4*)in)[i];
    union { bf16_t b[4]; uint64_t u; } o;
    o.b[0] = (bf16_t)v.x; o.b[1] = (bf16_t)v.y;
    o.b[2] = (bf16_t)v.z; o.b[3] = (bf16_t)v.w;
    *(uint64_t*)(out + (size_t)i * 4) = o.u;
  } else {
    const int tb = bid - 5120;            // 0..3071
    const int bx = (tb % 96) * 32;        // col of W
    const int by = (tb / 96) * 32;        // row of W
    const int tx = threadIdx.x & 31, ty = threadIdx.x >> 5;  // (32,8)
#pragma unroll
    for (int i = 0; i < 32; i += 8)
      tile[ty + i][tx] = W[(size_t)(by + ty + i) * 3072 + bx + tx];
    __syncthreads();
#pragma unroll
    for (int i = 0; i < 32; i += 8)
      Wt[(size_t)(bx + ty + i) * 1024 + by + tx] = (bf16_t)tile[tx][ty + i];
  }
}

// ---------------- bf16 GEMM, C = A @ Bt^T : 128^2, BK=32, counted vmcnt ----
// r9 fragment/staging layout (16KB per buffer) + double-buffer + counted
// vmcnt(4): next tile's 4 loads/thread stay in flight across the barrier
// (removes the m97 vmcnt(0) drain). LDS 32KB -> occupancy unchanged vs r9.
// MODE 0: scatter into Q/K/Vt head layouts.  MODE 1: +bias, fp32 out.
template <int MODE>
__global__ __launch_bounds__(256) void gemm_bt_kernel(
    const bf16_t* __restrict__ A, const bf16_t* __restrict__ Bt,
    bf16_t* __restrict__ Qo, bf16_t* __restrict__ Ko, bf16_t* __restrict__ Vto,
    const float* __restrict__ bias, float* __restrict__ Co,
    int nbx, int cpx) {
  __shared__ bf16_t As[2][4096];
  __shared__ bf16_t Bs[2][4096];
  const int tid = threadIdx.x;
  const int lane = tid & 63;
  const int wid = tid >> 6;
  const int wr = wid >> 1, wc = wid & 1;
  const int g = lane >> 4, lr = lane & 15;
  const int d_ = blockIdx.x;
  const int orig = (d_ & 7) * cpx + (d_ >> 3);
  const int brow = (orig / nbx) * 128;
  const int bcol = (orig % nbx) * 128;

  f32x4 acc[4][4] = {};

  // per-thread staging: 2 A-chunks + 2 B-chunks of 16B per K-tile
  const int idx0 = wid * 128 + lane;
  const int idx1 = wid * 128 + 64 + lane;
  const int row0 = idx0 >> 2, part0 = (idx0 & 3) * 8;
  const int row1 = idx1 >> 2, part1 = (idx1 & 3) * 8;
  const int dst0 = (wid * 128) * 8;        // elem offset of chunk group 0
  const int dst1 = (wid * 128 + 64) * 8;

  auto stage = [&](int t, int b) {
    async_ld16(A + (size_t)(brow + row0) * 1024 + t * 32 + part0, &As[b][dst0]);
    async_ld16(Bt + (size_t)(bcol + row0) * 1024 + t * 32 + part0, &Bs[b][dst0]);
    async_ld16(A + (size_t)(brow + row1) * 1024 + t * 32 + part1, &As[b][dst1]);
    async_ld16(Bt + (size_t)(bcol + row1) * 1024 + t * 32 + part1, &Bs[b][dst1]);
  };

  stage(0, 0);
  for (int t = 0; t < 32; ++t) {
    if (t + 1 < 32) {
      stage(t + 1, (t + 1) & 1);
      asm volatile("s_waitcnt vmcnt(4)" ::: "memory");  // tile t landed; t+1 in flight
    } else {
      asm volatile("s_waitcnt vmcnt(0)" ::: "memory");
    }
    __builtin_amdgcn_s_barrier();
    __builtin_amdgcn_sched_barrier(0);

    const bf16_t* as = As[t & 1];
    const bf16_t* bs = Bs[t & 1];
    bf16x8 af[4], bfr[4];
#pragma unroll
    for (int i = 0; i < 4; ++i) {
      af[i]  = *(const bf16x8*)&as[(wr * 64 + i * 16 + lr) * 32 + g * 8];
      bfr[i] = *(const bf16x8*)&bs[(wc * 64 + i * 16 + lr) * 32 + g * 8];
    }
    __builtin_amdgcn_s_setprio(1);
#pragma unroll
    for (int i = 0; i < 4; ++i)
#pragma unroll
      for (int j = 0; j < 4; ++j)
        acc[i][j] = __builtin_amdgcn_mfma_f32_16x16x32_bf16(af[i], bfr[j], acc[i][j], 0, 0, 0);
    __builtin_amdgcn_s_setprio(0);
    asm volatile("s_waitcnt lgkmcnt(0)" ::: "memory");  // reads retired before overwrite
    __builtin_amdgcn_s_barrier();
  }

#pragma unroll
  for (int i = 0; i < 4; ++i) {
    int row0_ = brow + wr * 64 + i * 16 + g * 4;
#pragma unroll
    for (int j = 0; j < 4; ++j) {
      int col = bcol + wc * 64 + j * 16 + lr;
#pragma unroll
      for (int r = 0; r < 4; ++r) {
        int row = row0_ + r;
        float v = acc[i][j][r];
        if (MODE == 0) {
          int n = row >> 11, t = row & (T_S - 1);
          int which = col >> 10, d = col & (D_M - 1);
          int h = d >> 6, dh = d & 63;
          if (which == 0)
            Qo[((size_t)(n * H_N + h) * T_S + t) * D_H + dh] = (bf16_t)v;
          else if (which == 1)
            Ko[((size_t)(n * H_N + h) * T_S + t) * D_H + dh] = (bf16_t)v;
          else
            Vto[((size_t)(n * H_N + h) * D_H + dh) * T_S + t] = (bf16_t)v;
        } else {
          Co[(size_t)row * D_M + col] = v + bias[col];
        }
      }
    }
  }
}

// ---------------- causal flash attention (swapped-QK, 32x32 MFMA) ----------
// (r9 structure, unchanged)
__global__ __launch_bounds__(256, 4) void attn_kernel(const bf16_t* __restrict__ Q,
                                                      const bf16_t* __restrict__ K,
                                                      const bf16_t* __restrict__ Vt,
                                                      bf16_t* __restrict__ O) {
  __shared__ bf16_t Ks[2][4096];
  __shared__ bf16_t Vs[2][4096];
  __shared__ float Linv[64];

  const int tid = threadIdx.x;
  const int lane = tid & 63;
  const int w = tid >> 6;
  const int qsub = w >> 1, khalf = w & 1;
  const int l31 = lane & 31;
  const int hi = lane >> 5;

  const int d_ = blockIdx.x;       // 0..1023
  const int x = d_ & 7;
  const int s = d_ >> 3;
  const int hs = s & 3, j_ = s >> 2;
  const int t_ = j_ >> 3, m_ = j_ & 7;
  const int qc = (t_ == 0) ? (31 - m_) : (t_ == 1) ? (16 + m_)
               : (t_ == 2) ? (15 - m_) : m_;
  const int nh = x * 4 + hs;
  const bf16_t* Qg = Q + (size_t)nh * T_S * D_H;
  const char* Kb = (const char*)(K + (size_t)nh * T_S * D_H);
  const char* Vb = (const char*)(Vt + (size_t)nh * D_H * T_S);
  const int n = nh >> 4, h = nh & 15;

  const int c0 = (w * 2 + 0) * 64 + lane;
  const int c1 = (w * 2 + 1) * 64 + lane;
  const int r0_ = c0 >> 3, cb0 = (c0 & 7) * 16, sw0 = (r0_ & 7) << 4;
  const int r1_ = c1 >> 3, cb1 = (c1 & 7) * 16, sw1 = (r1_ & 7) << 4;
  const int koff0 = r0_ * 128 + (cb0 ^ sw0), koff1 = r1_ * 128 + (cb1 ^ sw1);
  const int voff0 = r0_ * 4096 + (cb0 ^ sw0), voff1 = r1_ * 4096 + (cb1 ^ sw1);
  const int lds0 = (w * 2 + 0) * 1024, lds1 = (w * 2 + 1) * 1024;

  const int q0w = qc * 64 + qsub * 32;
  const int nt = qc + 1;

  bf16x8 qf[4];
#pragma unroll
  for (int ksd = 0; ksd < 4; ++ksd) {
    bf16x8 t = *(const bf16x8*)(Qg + (size_t)(q0w + l31) * D_H + ksd * 16 + hi * 8);
#pragma unroll
    for (int e = 0; e < 8; ++e) t[e] = (bf16_t)((float)t[e] * 0.125f);
    qf[ksd] = t;
  }

  const int kabs_ = khalf * 32 + l31;
  int kfo[4];
#pragma unroll
  for (int ksd = 0; ksd < 4; ++ksd)
    kfo[ksd] = (kabs_ * 128 + ksd * 32 + hi * 16) ^ ((kabs_ & 7) << 4);
  int vfo[2][2];
#pragma unroll
  for (int db = 0; db < 2; ++db)
#pragma unroll
    for (int kk = 0; kk < 2; ++kk) {
      int dd = db * 32 + l31;
      vfo[db][kk] = (dd * 128 + khalf * 64 + kk * 32 + hi * 16) ^ ((dd & 7) << 4);
    }

  f32x16 oacc[2] = {};
  float lsum = 0.f;

  auto issue = [&](int t, int b) {
    const char* kt_ = Kb + (size_t)t * 8192;
    const char* vt_ = Vb + (size_t)t * 128;
    async_ld16(kt_ + koff0, (char*)Ks[b] + lds0);
    async_ld16(kt_ + koff1, (char*)Ks[b] + lds1);
    async_ld16(vt_ + voff0, (char*)Vs[b] + lds0);
    async_ld16(vt_ + voff1, (char*)Vs[b] + lds1);
  };

  auto compute = [&](int kt, int b, bool domask) {
    f32x16 S = {};
    __builtin_amdgcn_s_setprio(1);
#pragma unroll
    for (int ksd = 0; ksd < 4; ++ksd) {
      bf16x8 kf = *(const bf16x8*)((char*)Ks[b] + kfo[ksd]);
      S = __builtin_amdgcn_mfma_f32_32x32x16_bf16(kf, qf[ksd], S, 0, 0, 0);
    }
    __builtin_amdgcn_s_setprio(0);

    if (domask) {
#pragma unroll
      for (int r = 0; r < 16; ++r) {
        int ktile = khalf * 32 + (r & 3) + 8 * (r >> 2) + 4 * hi;
        if (kt * 64 + ktile > q0w + l31) S[r] = -1.0e30f;
      }
    }

    float p[16];
#pragma unroll
    for (int r = 0; r < 16; ++r) {
      p[r] = __builtin_amdgcn_exp2f(fminf(S[r] * 1.442695041f, 50.f));
      lsum += p[r];
    }

    uint32_t dw[8];
#pragma unroll
    for (int i = 0; i < 8; ++i) {
      union { bf16_t b2[2]; uint32_t u; } pk;
      pk.b2[0] = (bf16_t)p[2 * i];
      pk.b2[1] = (bf16_t)p[2 * i + 1];
      dw[i] = pk.u;
    }

    bf16x8 pa[2];
#pragma unroll
    for (int kk = 0; kk < 2; ++kk) {
      uint32_t u0 = dw[kk * 4 + 0], u1 = dw[kk * 4 + 1];
      uint32_t u2 = dw[kk * 4 + 2], u3 = dw[kk * 4 + 3];
      uint32_t sa = __shfl_xor(hi ? u0 : u2, 32, 64);
      uint32_t sb = __shfl_xor(hi ? u1 : u3, 32, 64);
      union { uint32_t u[4]; bf16x8 v; } f;
      f.u[0] = hi ? sa : u0;
      f.u[1] = hi ? sb : u1;
      f.u[2] = hi ? u2 : sa;
      f.u[3] = hi ? u3 : sb;
      pa[kk] = f.v;
    }

    __builtin_amdgcn_s_setprio(1);
#pragma unroll
    for (int db = 0; db < 2; ++db)
#pragma unroll
      for (int kk = 0; kk < 2; ++kk) {
        bf16x8 vf = *(const bf16x8*)((char*)Vs[b] + vfo[db][kk]);
        oacc[db] = __builtin_amdgcn_mfma_f32_32x32x16_bf16(pa[kk], vf, oacc[db], 0, 0, 0);
      }
    __builtin_amdgcn_s_setprio(0);
  };

  issue(0, 0);
  int buf = 0;
  for (int kt = 0; kt < nt; ++kt) {
    asm volatile("s_waitcnt vmcnt(0)" ::: "memory");
    __builtin_amdgcn_s_barrier();
    __builtin_amdgcn_sched_barrier(0);
    if (kt + 1 < nt) issue(kt + 1, buf ^ 1);
    compute(kt, buf, kt == nt - 1);
    buf ^= 1;
  }

  lsum += __shfl_xor(lsum, 32, 64);

  __syncthreads();
  float* mO = (float*)Ks;
  float* mL = (float*)Vs;
  if (khalf == 1) {
    float* ob = mO + qsub * 2048;
#pragma unroll
    for (int db = 0; db < 2; ++db)
#pragma unroll
      for (int r = 0; r < 16; ++r)
        ob[(db * 16 + r) * 64 + lane] = oacc[db][r];
    mL[qsub * 32 + l31] = lsum;
  }
  __syncthreads();
  if (khalf == 0) {
    float* ob = mO + qsub * 2048;
    float ltot = lsum + mL[qsub * 32 + l31];
    Linv[qsub * 32 + l31] = 1.f / ltot;
#pragma unroll
    for (int db = 0; db < 2; ++db)
#pragma unroll
      for (int r = 0; r < 16; ++r)
        oacc[db][r] += ob[(db * 16 + r) * 64 + lane];
#pragma unroll
    for (int r = 0; r < 16; ++r) {
      int ro = (r & 3) + 8 * (r >> 2) + 4 * hi;
      int qrow = q0w + ro;
      float inv = Linv[qsub * 32 + ro];
#pragma unroll
      for (int db = 0; db < 2; ++db)
        O[(size_t)(n * T_S + qrow) * D_M + h * D_H + db * 32 + l31] =
            (bf16_t)(oacc[db][r] * inv);
    }
  }
}

extern "C" void kernel_launch(void* const* d_in, const int* in_sizes, int n_in,
                              void* d_out, int out_size, void* d_ws, size_t ws_size,
                              hipStream_t stream) {
  const float* x  = (const float*)d_in[0];
  const float* W  = (const float*)d_in[1];
  const float* pw = (const float*)d_in[2];
  const float* pb = (const float*)d_in[3];
  float* out = (float*)d_out;

  char* ws = (char*)d_ws;
  bf16_t* x_bf = (bf16_t*)(ws);                      //  8 MB: [4096][1024]
  bf16_t* Wt   = (bf16_t*)(ws + (8ull  << 20));      //  6 MB: [3072][1024]
  bf16_t* pwb  = (bf16_t*)(ws + (14ull << 20));      //  2 MB: [1024][1024]
  bf16_t* Qh   = (bf16_t*)(ws + (16ull << 20));      //  8 MB: [2,16,2048,64]
  bf16_t* Kh   = (bf16_t*)(ws + (24ull << 20));      //  8 MB
  bf16_t* Vth  = (bf16_t*)(ws + (32ull << 20));      //  8 MB: [2,16,64,2048]
  bf16_t* Oa   = (bf16_t*)(ws + (40ull << 20));      //  8 MB: [4096][1024]

  // all input prep in one launch: 5120 cvt blocks + 3072 transpose blocks
  prep_kernel<<<8192, 256, 0, stream>>>(x, x_bf, pw, pwb, W, Wt);

  // QKV GEMM: M=4096 (32), N=3072 (24) -> 768 blocks, cpx=96
  gemm_bt_kernel<0><<<768, 256, 0, stream>>>(x_bf, Wt, Qh, Kh, Vth, nullptr, nullptr, 24, 96);

  attn_kernel<<<1024, 256, 0, stream>>>(Qh, Kh, Vth, Oa);

  // proj GEMM: M=4096 (32), N=1024 (8) -> 256 blocks, cpx=32
  gemm_bt_kernel<1><<<256, 256, 0, stream>>>(Oa, pwb, nullptr, nullptr, nullptr, pb, out, 8, 32);
}